// Round 2
// baseline (54.293 us; speedup 1.0000x reference)
//
#include <hip/hip_runtime.h>
#include <stdint.h>

#define BTOT 8192
#define NSS  4096
#define LL   64
#define BT   32            // batches per workgroup
#define STT  32            // states per tile
#define NT   (NSS/STT)     // 128 state tiles total
#define NSPLIT 4           // state splits across blocks
#define TPS  (NT/NSPLIT)   // 32 tiles per split
#define JROWB 80           // padded LDS row bytes for J tile

typedef __bf16 bf16x8 __attribute__((ext_vector_type(8)));
typedef float  f32x4  __attribute__((ext_vector_type(4)));

static __device__ __forceinline__ unsigned short f2bf(float x){
  union { float f; uint32_t u; } v; v.f = x;
  uint32_t r = v.u + 0x7fffu + ((v.u >> 16) & 1u);
  return (unsigned short)(r >> 16);
}
static __device__ __forceinline__ float bf2f(unsigned short b){
  union { uint32_t u; float f; } v; v.u = ((uint32_t)b) << 16; return v.f;
}

// Build S in bf16 (row-major [NS][64]) and S^T in bf16 ([64][NS]) in workspace.
__global__ void prepack_kernel(const float* __restrict__ S,
                               unsigned short* __restrict__ Sb,
                               unsigned short* __restrict__ STb){
  int i = blockIdx.x * blockDim.x + threadIdx.x;   // grid covers NS*L exactly
  Sb[i] = f2bf(S[i]);
  int l = i >> 12;                                  // i = l*4096 + s
  int s = i & (NSS - 1);
  STb[i] = f2bf(S[s * LL + l]);
}

__launch_bounds__(256, 4)
__global__ void fused_kernel(const float* __restrict__ f,
                             const unsigned short* __restrict__ Sb,
                             const unsigned short* __restrict__ STb,
                             float* __restrict__ numP,    // [BTOT*LL], pre-zeroed
                             float* __restrict__ zP){     // [BTOT], pre-zeroed
  const int tid  = threadIdx.x;
  const int w    = tid >> 6;       // wave id 0..3
  const int lane = tid & 63;
  const int c16  = lane & 15;
  const int q4   = lane >> 4;      // 0..3
  const int bt   = blockIdx.x & 255;
  const int sp   = blockIdx.x >> 8;          // state split 0..3
  const int bb   = bt * BT;

  __shared__ unsigned char jraw[4][32 * JROWB];  // per-wave J tile [32 batches][32 states bf16]
  __shared__ float nredH[4][32 * 33];            // half-label cross-wave reduce buffer
  __shared__ float zred[4][128];

  // ---- prologue: f B-fragments with hi/lo bf16 split ----
  // B-frag layout: col = lane&15 (batch), k = (lane>>4)*8 + j (label)
  bf16x8 fhi[2][2], flo[2][2];
  #pragma unroll
  for (int g = 0; g < 2; ++g){
    const float* frow = f + (size_t)(bb + g*16 + c16) * LL;
    #pragma unroll
    for (int kc = 0; kc < 2; ++kc){
      float vv[8];
      *(float4*)&vv[0] = *(const float4*)&frow[kc*32 + 8*q4];
      *(float4*)&vv[4] = *(const float4*)&frow[kc*32 + 8*q4 + 4];
      union { unsigned short u[8]; bf16x8 v; } H, Lo;
      #pragma unroll
      for (int j = 0; j < 8; ++j){
        unsigned short h = f2bf(vv[j]);
        H.u[j]  = h;
        Lo.u[j] = f2bf(vv[j] - bf2f(h));
      }
      fhi[g][kc] = H.v; flo[g][kc] = Lo.v;
    }
  }

  f32x4 acc2[4][2];
  #pragma unroll
  for (int lt = 0; lt < 4; ++lt)
    #pragma unroll
    for (int g = 0; g < 2; ++g) acc2[lt][g] = (f32x4){0.f,0.f,0.f,0.f};
  float zpart[2] = {0.f, 0.f};

  unsigned char* jb = jraw[w];

  // ---- main loop: this block owns tiles [sp*TPS, sp*TPS+TPS); waves interleave ----
  for (int i = w; i < TPS; i += 4){
    const int sbase = (sp * TPS + i) * STT;

    // GEMM1: potential = S @ f^T (A = S rows, exact in bf16; hi/lo for f)
    bf16x8 a1[2][2];
    #pragma unroll
    for (int ss = 0; ss < 2; ++ss)
      #pragma unroll
      for (int kc = 0; kc < 2; ++kc)
        a1[ss][kc] = *(const bf16x8*)&Sb[(size_t)(sbase + ss*16 + c16)*LL + kc*32 + 8*q4];

    f32x4 acc1[2][2];
    #pragma unroll
    for (int ss = 0; ss < 2; ++ss)
      #pragma unroll
      for (int g = 0; g < 2; ++g){
        f32x4 a = (f32x4){0.f,0.f,0.f,0.f};
        #pragma unroll
        for (int kc = 0; kc < 2; ++kc){
          a = __builtin_amdgcn_mfma_f32_16x16x32_bf16(a1[ss][kc], fhi[g][kc], a, 0,0,0);
          a = __builtin_amdgcn_mfma_f32_16x16x32_bf16(a1[ss][kc], flo[g][kc], a, 0,0,0);
        }
        acc1[ss][g] = a;
      }

    // exp -> z partial -> pack bf16 -> per-wave LDS (transposed)
    #pragma unroll
    for (int ss = 0; ss < 2; ++ss)
      #pragma unroll
      for (int g = 0; g < 2; ++g){
        float J0 = __expf(acc1[ss][g][0]);
        float J1 = __expf(acc1[ss][g][1]);
        float J2 = __expf(acc1[ss][g][2]);
        float J3 = __expf(acc1[ss][g][3]);
        zpart[g] += (J0 + J1) + (J2 + J3);
        uint32_t w0 = (uint32_t)f2bf(J0) | ((uint32_t)f2bf(J1) << 16);
        uint32_t w1 = (uint32_t)f2bf(J2) | ((uint32_t)f2bf(J3) << 16);
        int row = g*16 + c16;
        *(uint2*)&jb[row*JROWB + ss*32 + q4*8] = make_uint2(w0, w1);
      }

    // GEMM2: num[l, b] += S^T @ J
    bf16x8 b2[2];
    #pragma unroll
    for (int g = 0; g < 2; ++g){
      int row = g*16 + c16;
      b2[g] = *(const bf16x8*)&jb[row*JROWB + q4*16];
    }
    #pragma unroll
    for (int lt = 0; lt < 4; ++lt){
      bf16x8 a2 = *(const bf16x8*)&STb[(size_t)(lt*16 + c16)*NSS + sbase + 8*q4];
      #pragma unroll
      for (int g = 0; g < 2; ++g)
        acc2[lt][g] = __builtin_amdgcn_mfma_f32_16x16x32_bf16(a2, b2[g], acc2[lt][g], 0,0,0);
    }
  }

  // ---- epilogue: cross-wave reduce (two label-halves to halve LDS), atomic to global ----
  // stage A: zred + half-0 labels (lt 0,1)
  zred[w][q4*32 + c16]      = zpart[0];
  zred[w][q4*32 + 16 + c16] = zpart[1];
  #pragma unroll
  for (int lt = 0; lt < 2; ++lt)
    #pragma unroll
    for (int g = 0; g < 2; ++g)
      #pragma unroll
      for (int jj = 0; jj < 4; ++jj){
        int l = lt*16 + q4*4 + jj;     // 0..31
        int b = g*16 + c16;
        nredH[w][l*33 + b] = acc2[lt][g][jj];
      }
  __syncthreads();
  // stage B
  if (tid < BT){
    float zz = 0.f;
    #pragma unroll
    for (int ww = 0; ww < 4; ++ww)
      #pragma unroll
      for (int qq = 0; qq < 4; ++qq) zz += zred[ww][qq*32 + tid];
    atomicAdd(&zP[bb + tid], zz);
  }
  #pragma unroll
  for (int it = 0; it < 4; ++it){
    int idx = it*256 + tid;            // 0..1023
    int b = idx >> 5, l = idx & 31;    // consecutive l -> coalesced atomics
    float v = (nredH[0][l*33+b] + nredH[1][l*33+b]) + (nredH[2][l*33+b] + nredH[3][l*33+b]);
    atomicAdd(&numP[(size_t)(bb + b)*LL + l], v);
  }
  __syncthreads();
  // stage C: half-1 labels (lt 2,3)
  #pragma unroll
  for (int lt = 0; lt < 2; ++lt)
    #pragma unroll
    for (int g = 0; g < 2; ++g)
      #pragma unroll
      for (int jj = 0; jj < 4; ++jj){
        int l = lt*16 + q4*4 + jj;
        int b = g*16 + c16;
        nredH[w][l*33 + b] = acc2[2+lt][g][jj];
      }
  __syncthreads();
  // stage D
  #pragma unroll
  for (int it = 0; it < 4; ++it){
    int idx = it*256 + tid;
    int b = idx >> 5, l = idx & 31;
    float v = (nredH[0][l*33+b] + nredH[1][l*33+b]) + (nredH[2][l*33+b] + nredH[3][l*33+b]);
    atomicAdd(&numP[(size_t)(bb + b)*LL + 32 + l], v);
  }
}

// finalize: p = num/z, BCE, per-block loss partials
__global__ void finalize_kernel(const float* __restrict__ numP,
                                const float* __restrict__ zP,
                                const float* __restrict__ y,
                                const float* __restrict__ mask,
                                float* __restrict__ out,     // [1 + BTOT*LL]
                                float* __restrict__ parts){  // [2048]
  int tid = threadIdx.x;
  int idx = blockIdx.x * 256 + tid;      // 0 .. BTOT*LL-1
  float num = numP[idx];
  float z   = zP[idx >> 6];
  float p = fminf(num / z, 1.0f);
  out[1 + idx] = p;
  float lg = fmaxf(__logf(p), -100.f);
  float l1 = fmaxf(log1pf(-p), -100.f);
  float yv = y[idx], mv = mask[idx];
  float lsum = -(yv*lg + (1.f - yv)*l1) * mv;
  #pragma unroll
  for (int off = 32; off; off >>= 1) lsum += __shfl_down(lsum, off);
  __shared__ float wred[4];
  int w = tid >> 6, lane = tid & 63;
  if (lane == 0) wred[w] = lsum;
  __syncthreads();
  if (tid == 0) parts[blockIdx.x] = (wred[0] + wred[1]) + (wred[2] + wred[3]);
}

__global__ void loss_kernel(const float* __restrict__ parts, float* __restrict__ out){
  float v = 0.f;
  #pragma unroll
  for (int i = 0; i < 8; ++i) v += parts[threadIdx.x + 256*i];
  #pragma unroll
  for (int off = 32; off; off >>= 1) v += __shfl_down(v, off);
  __shared__ float sred[4];
  int w = threadIdx.x >> 6, lane = threadIdx.x & 63;
  if (lane == 0) sred[w] = v;
  __syncthreads();
  if (threadIdx.x == 0)
    out[0] = ((sred[0] + sred[1]) + (sred[2] + sred[3])) * (1.0f / ((float)BTOT * (float)LL));
}

extern "C" void kernel_launch(void* const* d_in, const int* in_sizes, int n_in,
                              void* d_out, int out_size, void* d_ws, size_t ws_size,
                              hipStream_t stream){
  const float* f = (const float*)d_in[0];
  const float* y = (const float*)d_in[1];
  const float* m = (const float*)d_in[2];
  const float* S = (const float*)d_in[3];
  float* out = (float*)d_out;

  unsigned short* Sb  = (unsigned short*)d_ws;                 // 512 KB
  unsigned short* STb = Sb + (size_t)NSS * LL;                 // 512 KB
  char* p = (char*)d_ws + (size_t)2 * NSS * LL * sizeof(unsigned short);
  float* numP  = (float*)p;            p += (size_t)BTOT * LL * sizeof(float);   // 2 MB
  float* zP    = (float*)p;            p += (size_t)BTOT * sizeof(float);        // 32 KB
  float* parts = (float*)p;                                                      // 8 KB

  hipMemsetAsync(numP, 0, ((size_t)BTOT * LL + BTOT) * sizeof(float), stream);
  prepack_kernel<<<(NSS*LL)/256, 256, 0, stream>>>(S, Sb, STb);
  fused_kernel<<<256 * NSPLIT, 256, 0, stream>>>(f, Sb, STb, numP, zP);
  finalize_kernel<<<(BTOT*LL)/256, 256, 0, stream>>>(numP, zP, y, m, out, parts);
  loss_kernel<<<1, 256, 0, stream>>>(parts, out);
}

// Round 3
// 53.508 us; speedup vs baseline: 1.0147x; 1.0147x over previous
//
#include <hip/hip_runtime.h>
#include <stdint.h>

#define BTOT 8192
#define NSS  4096
#define LL   64
#define BT   32            // batches per workgroup
#define STT  32            // states per tile
#define NT   (NSS/STT)     // 128 state tiles total
#define NSPLIT 4           // state splits across blocks
#define TPS  (NT/NSPLIT)   // 32 tiles per split
#define JROWB 80           // padded LDS row bytes for J tile

typedef __bf16 bf16x8 __attribute__((ext_vector_type(8)));
typedef float  f32x4  __attribute__((ext_vector_type(4)));

static __device__ __forceinline__ unsigned short f2bf(float x){
  union { float f; uint32_t u; } v; v.f = x;
  uint32_t r = v.u + 0x7fffu + ((v.u >> 16) & 1u);
  return (unsigned short)(r >> 16);
}
static __device__ __forceinline__ float bf2f(unsigned short b){
  union { uint32_t u; float f; } v; v.u = ((uint32_t)b) << 16; return v.f;
}

// Build S in bf16 (row-major [NS][64]) and S^T in bf16 ([64][NS]) in workspace.
__global__ void prepack_kernel(const float* __restrict__ S,
                               unsigned short* __restrict__ Sb,
                               unsigned short* __restrict__ STb){
  int i = blockIdx.x * blockDim.x + threadIdx.x;   // grid covers NS*L exactly
  Sb[i] = f2bf(S[i]);
  int l = i >> 12;                                  // i = l*4096 + s
  int s = i & (NSS - 1);
  STb[i] = f2bf(S[s * LL + l]);
}

__launch_bounds__(256, 4)
__global__ void fused_kernel(const float* __restrict__ f,
                             const unsigned short* __restrict__ Sb,
                             const unsigned short* __restrict__ STb,
                             float* __restrict__ numPart,   // [NSPLIT][BTOT][LL]
                             float* __restrict__ zPart){    // [NSPLIT][BTOT]
  const int tid  = threadIdx.x;
  const int w    = tid >> 6;       // wave id 0..3
  const int lane = tid & 63;
  const int c16  = lane & 15;
  const int q4   = lane >> 4;      // 0..3
  const int bt   = blockIdx.x & 255;
  const int sp   = blockIdx.x >> 8;          // state split 0..3
  const int bb   = bt * BT;

  __shared__ unsigned char jraw[4][32 * JROWB];  // per-wave J tile [32 batches][32 states bf16]
  __shared__ float nredH[4][32 * 33];            // half-label cross-wave reduce buffer
  __shared__ float zred[4][128];

  // ---- prologue: f B-fragments with hi/lo bf16 split ----
  // B-frag layout: col = lane&15 (batch), k = (lane>>4)*8 + j (label)
  bf16x8 fhi[2][2], flo[2][2];
  #pragma unroll
  for (int g = 0; g < 2; ++g){
    const float* frow = f + (size_t)(bb + g*16 + c16) * LL;
    #pragma unroll
    for (int kc = 0; kc < 2; ++kc){
      float vv[8];
      *(float4*)&vv[0] = *(const float4*)&frow[kc*32 + 8*q4];
      *(float4*)&vv[4] = *(const float4*)&frow[kc*32 + 8*q4 + 4];
      union { unsigned short u[8]; bf16x8 v; } H, Lo;
      #pragma unroll
      for (int j = 0; j < 8; ++j){
        unsigned short h = f2bf(vv[j]);
        H.u[j]  = h;
        Lo.u[j] = f2bf(vv[j] - bf2f(h));
      }
      fhi[g][kc] = H.v; flo[g][kc] = Lo.v;
    }
  }

  f32x4 acc2[4][2];
  #pragma unroll
  for (int lt = 0; lt < 4; ++lt)
    #pragma unroll
    for (int g = 0; g < 2; ++g) acc2[lt][g] = (f32x4){0.f,0.f,0.f,0.f};
  float zpart[2] = {0.f, 0.f};

  unsigned char* jb = jraw[w];

  // ---- main loop: this block owns tiles [sp*TPS, sp*TPS+TPS); waves interleave ----
  for (int i = w; i < TPS; i += 4){
    const int sbase = (sp * TPS + i) * STT;

    // GEMM1: potential = S @ f^T (A = S rows, exact in bf16; hi/lo for f)
    bf16x8 a1[2][2];
    #pragma unroll
    for (int ss = 0; ss < 2; ++ss)
      #pragma unroll
      for (int kc = 0; kc < 2; ++kc)
        a1[ss][kc] = *(const bf16x8*)&Sb[(size_t)(sbase + ss*16 + c16)*LL + kc*32 + 8*q4];

    f32x4 acc1[2][2];
    #pragma unroll
    for (int ss = 0; ss < 2; ++ss)
      #pragma unroll
      for (int g = 0; g < 2; ++g){
        f32x4 a = (f32x4){0.f,0.f,0.f,0.f};
        #pragma unroll
        for (int kc = 0; kc < 2; ++kc){
          a = __builtin_amdgcn_mfma_f32_16x16x32_bf16(a1[ss][kc], fhi[g][kc], a, 0,0,0);
          a = __builtin_amdgcn_mfma_f32_16x16x32_bf16(a1[ss][kc], flo[g][kc], a, 0,0,0);
        }
        acc1[ss][g] = a;
      }

    // exp -> z partial -> pack bf16 -> per-wave LDS (transposed)
    #pragma unroll
    for (int ss = 0; ss < 2; ++ss)
      #pragma unroll
      for (int g = 0; g < 2; ++g){
        float J0 = __expf(acc1[ss][g][0]);
        float J1 = __expf(acc1[ss][g][1]);
        float J2 = __expf(acc1[ss][g][2]);
        float J3 = __expf(acc1[ss][g][3]);
        zpart[g] += (J0 + J1) + (J2 + J3);
        uint32_t w0 = (uint32_t)f2bf(J0) | ((uint32_t)f2bf(J1) << 16);
        uint32_t w1 = (uint32_t)f2bf(J2) | ((uint32_t)f2bf(J3) << 16);
        int row = g*16 + c16;
        *(uint2*)&jb[row*JROWB + ss*32 + q4*8] = make_uint2(w0, w1);
      }

    // GEMM2: num[l, b] += S^T @ J
    bf16x8 b2[2];
    #pragma unroll
    for (int g = 0; g < 2; ++g){
      int row = g*16 + c16;
      b2[g] = *(const bf16x8*)&jb[row*JROWB + q4*16];
    }
    #pragma unroll
    for (int lt = 0; lt < 4; ++lt){
      bf16x8 a2 = *(const bf16x8*)&STb[(size_t)(lt*16 + c16)*NSS + sbase + 8*q4];
      #pragma unroll
      for (int g = 0; g < 2; ++g)
        acc2[lt][g] = __builtin_amdgcn_mfma_f32_16x16x32_bf16(a2, b2[g], acc2[lt][g], 0,0,0);
    }
  }

  // ---- epilogue: cross-wave reduce in LDS (two label-halves), plain store to split slab ----
  float* numOut = numPart + (size_t)sp * BTOT * LL + (size_t)bb * LL;
  // stage A: zred + half-0 labels (lt 0,1)
  zred[w][q4*32 + c16]      = zpart[0];
  zred[w][q4*32 + 16 + c16] = zpart[1];
  #pragma unroll
  for (int lt = 0; lt < 2; ++lt)
    #pragma unroll
    for (int g = 0; g < 2; ++g)
      #pragma unroll
      for (int jj = 0; jj < 4; ++jj){
        int l = lt*16 + q4*4 + jj;     // 0..31
        int b = g*16 + c16;
        nredH[w][l*33 + b] = acc2[lt][g][jj];
      }
  __syncthreads();
  // stage B
  if (tid < BT){
    float zz = 0.f;
    #pragma unroll
    for (int ww = 0; ww < 4; ++ww)
      #pragma unroll
      for (int qq = 0; qq < 4; ++qq) zz += zred[ww][qq*32 + tid];
    zPart[(size_t)sp * BTOT + bb + tid] = zz;
  }
  #pragma unroll
  for (int it = 0; it < 4; ++it){
    int idx = it*256 + tid;            // 0..1023
    int b = idx >> 5, l = idx & 31;    // consecutive l -> coalesced stores
    float v = (nredH[0][l*33+b] + nredH[1][l*33+b]) + (nredH[2][l*33+b] + nredH[3][l*33+b]);
    numOut[(size_t)b*LL + l] = v;
  }
  __syncthreads();
  // stage C: half-1 labels (lt 2,3)
  #pragma unroll
  for (int lt = 0; lt < 2; ++lt)
    #pragma unroll
    for (int g = 0; g < 2; ++g)
      #pragma unroll
      for (int jj = 0; jj < 4; ++jj){
        int l = lt*16 + q4*4 + jj;
        int b = g*16 + c16;
        nredH[w][l*33 + b] = acc2[2+lt][g][jj];
      }
  __syncthreads();
  // stage D
  #pragma unroll
  for (int it = 0; it < 4; ++it){
    int idx = it*256 + tid;
    int b = idx >> 5, l = idx & 31;
    float v = (nredH[0][l*33+b] + nredH[1][l*33+b]) + (nredH[2][l*33+b] + nredH[3][l*33+b]);
    numOut[(size_t)b*LL + 32 + l] = v;
  }
}

// finalize: sum split partials, p = num/z, BCE, per-block loss partials
__global__ void finalize_kernel(const float* __restrict__ numPart,
                                const float* __restrict__ zPart,
                                const float* __restrict__ y,
                                const float* __restrict__ mask,
                                float* __restrict__ out,     // [1 + BTOT*LL]
                                float* __restrict__ parts){  // [2048]
  int tid = threadIdx.x;
  int idx = blockIdx.x * 256 + tid;      // 0 .. BTOT*LL-1
  int b = idx >> 6;
  float num = 0.f, z = 0.f;
  #pragma unroll
  for (int sp = 0; sp < NSPLIT; ++sp){
    num += numPart[(size_t)sp * BTOT * LL + idx];
    z   += zPart[(size_t)sp * BTOT + b];
  }
  float p = fminf(num / z, 1.0f);
  out[1 + idx] = p;
  float lg = fmaxf(__logf(p), -100.f);
  float l1 = fmaxf(log1pf(-p), -100.f);
  float yv = y[idx], mv = mask[idx];
  float lsum = -(yv*lg + (1.f - yv)*l1) * mv;
  #pragma unroll
  for (int off = 32; off; off >>= 1) lsum += __shfl_down(lsum, off);
  __shared__ float wred[4];
  int w = tid >> 6, lane = tid & 63;
  if (lane == 0) wred[w] = lsum;
  __syncthreads();
  if (tid == 0) parts[blockIdx.x] = (wred[0] + wred[1]) + (wred[2] + wred[3]);
}

__global__ void loss_kernel(const float* __restrict__ parts, float* __restrict__ out){
  float v = 0.f;
  #pragma unroll
  for (int i = 0; i < 8; ++i) v += parts[threadIdx.x + 256*i];
  #pragma unroll
  for (int off = 32; off; off >>= 1) v += __shfl_down(v, off);
  __shared__ float sred[4];
  int w = threadIdx.x >> 6, lane = threadIdx.x & 63;
  if (lane == 0) sred[w] = v;
  __syncthreads();
  if (threadIdx.x == 0)
    out[0] = ((sred[0] + sred[1]) + (sred[2] + sred[3])) * (1.0f / ((float)BTOT * (float)LL));
}

extern "C" void kernel_launch(void* const* d_in, const int* in_sizes, int n_in,
                              void* d_out, int out_size, void* d_ws, size_t ws_size,
                              hipStream_t stream){
  const float* f = (const float*)d_in[0];
  const float* y = (const float*)d_in[1];
  const float* m = (const float*)d_in[2];
  const float* S = (const float*)d_in[3];
  float* out = (float*)d_out;

  unsigned short* Sb  = (unsigned short*)d_ws;                 // 512 KB
  unsigned short* STb = Sb + (size_t)NSS * LL;                 // 512 KB
  char* p = (char*)d_ws + (size_t)2 * NSS * LL * sizeof(unsigned short);
  float* numPart = (float*)p;  p += (size_t)NSPLIT * BTOT * LL * sizeof(float);  // 8 MB
  float* zPart   = (float*)p;  p += (size_t)NSPLIT * BTOT * sizeof(float);       // 128 KB
  float* parts   = (float*)p;                                                    // 8 KB

  prepack_kernel<<<(NSS*LL)/256, 256, 0, stream>>>(S, Sb, STb);
  fused_kernel<<<256 * NSPLIT, 256, 0, stream>>>(f, Sb, STb, numPart, zPart);
  finalize_kernel<<<(BTOT*LL)/256, 256, 0, stream>>>(numPart, zPart, y, m, out, parts);
  loss_kernel<<<1, 256, 0, stream>>>(parts, out);
}